// Round 12
// baseline (372.834 us; speedup 1.0000x reference)
//
#include <hip/hip_runtime.h>
#include <stdint.h>

typedef unsigned short u16;
typedef __attribute__((ext_vector_type(8))) short bf16x8;
typedef __attribute__((ext_vector_type(4))) float f32x4;

__device__ __forceinline__ u16 f2bf(float f) {
  union { float f; uint32_t u; } v; v.f = f;
  uint32_t u = v.u;
  return (u16)((u + 0x7fffu + ((u >> 16) & 1u)) >> 16);
}

__device__ __forceinline__ void gl_lds16(const void* g, void* l) {
  __builtin_amdgcn_global_load_lds(
      (const __attribute__((address_space(1))) uint32_t*)g,
      (__attribute__((address_space(3))) uint32_t*)l, 16, 0, 0);
}

__constant__ int c_off[9] = {0, 1024, 1808, 2384, 2784, 3040, 3184, 3248, 3264};

// ---------------------------------------------------------------------------
// Fused prep kernel (R21 compressed scatter: grid 2576).
// ---------------------------------------------------------------------------
__global__ __launch_bounds__(256)
void prep_all(const float* __restrict__ x, u16* __restrict__ Xb,
              const float* __restrict__ lA, u16* __restrict__ lAb,
              const float* __restrict__ ip_w, u16* __restrict__ ip_wt,
              const float* __restrict__ out_w, u16* __restrict__ out_wt,
              const float* __restrict__ lB, u16* __restrict__ lBt,
              const float* w1, const float* w2, const float* w3, const float* w4,
              const float* w5, const float* w6, const float* w7, const float* w8,
              const float* __restrict__ cb,
              u16* __restrict__ Wct, float* __restrict__ bias_c) {
  __shared__ float tile[64][65];
  int b = blockIdx.x;
  const int t = threadIdx.x;
  if (b < 512) {
    const int i = b * 256 + t;
    const float4 v = ((const float4*)x)[i];
    ((ushort4*)Xb)[i] = make_ushort4(f2bf(v.x), f2bf(v.y), f2bf(v.z), f2bf(v.w));
    return;
  }
  b -= 512;
  if (b < 256) {
    const int i = b * 256 + t;
    const float4 v = ((const float4*)lA)[i];
    ((ushort4*)lAb)[i] = make_ushort4(f2bf(v.x), f2bf(v.y), f2bf(v.z), f2bf(v.w));
    return;
  }
  b -= 256;
  if (b < 1392) {
    const float* src; u16* dst; int R, C, bx, by;
    if (b < 816)        { src = ip_w;  dst = ip_wt;  R = 3264; C = 1024; bx = b % 16; by = b / 16; }
    else if (b < 1328)  { b -= 816;  src = out_w; dst = out_wt; R = 1024; C = 1968; bx = b % 32; by = b / 32; }
    else                { b -= 1328; src = lB;    dst = lBt;    R = 64;   C = 4096; bx = b;      by = 0; }
    const int rb = by << 6, cbs = bx << 6;
    for (int i = 0; i < 16; ++i) {
      const int idx = t + (i << 8);
      const int r = idx >> 6, c = idx & 63;
      float v = 0.f;
      if (cbs + c < C) v = src[(size_t)(rb + r) * C + cbs + c];
      tile[r][c] = v;
    }
    __syncthreads();
    const int c = t & 63, q = t >> 6;
    u16* dcol = dst + (size_t)(cbs + c) * R + rb;
    for (int v4 = 0; v4 < 4; ++v4) {
      const int r0 = (q << 4) + (v4 << 2);
      *(ushort4*)(dcol + r0) = make_ushort4(
          f2bf(tile[r0][c]), f2bf(tile[r0 + 1][c]),
          f2bf(tile[r0 + 2][c]), f2bf(tile[r0 + 3][c]));
    }
    return;
  }
  // Wct scatter: 8 rows per block. o0 in [0, 3328).
  const int o0 = (b - 1392) << 3;
  for (int i = t; i < 1024; i += 256)
    *(ushort4*)(Wct + (size_t)(o0 + (i >> 7)) * 512 + ((i & 127) << 2)) =
        make_ushort4(0, 0, 0, 0);
  __syncthreads();
  const float* ws[8] = {w1, w2, w3, w4, w5, w6, w7, w8};
  for (int rr = 0; rr < 8; ++rr) {
    const int o = o0 + rr;
    if (o >= 3264) {
      if (t == 0) bias_c[o] = 0.f;
      continue;
    }
    u16* row = Wct + (size_t)o * 512;
    int kidx = 0;
    while (o >= c_off[kidx + 1]) ++kidx;
    const int ks = kidx + 1;
    const int s  = 8 - kidx;
    const int r  = o - c_off[kidx];
    const int f   = r / (s * s);
    const int rem = r - f * s * s;
    const int oi  = rem / s;
    const int oj  = rem - oi * s;
    const float* w = ws[kidx] + (size_t)f * 8 * ks * ks;
    const int ne = 8 * ks * ks;
    for (int e = t; e < ne; e += 256) {
      const int c  = e / (ks * ks);
      const int er = e - c * ks * ks;
      const int di = er / ks;
      const int dj = er - di * ks;
      row[((oi + di) * 8 + (oj + dj)) * 8 + c] = f2bf(w[(c * ks + di) * ks + dj]);
    }
    if (t == 0) bias_c[o] = cb[kidx * 16 + f];
  }
}

// ---------------------------------------------------------------------------
// R15 GEMM body (the proven inner loop): 64x(NR*32) tile, 4 waves, BK=64,
// dbuf LDS via __syncthreads, XOR-swizzled, gl_lds staging.
// EPI 0: outf = acc (f32 partial)   EPI 1: relu(acc+st_in) -> outf?,outb
// EPI 2: acc+bias -> outf, cg<nvalid  EPI 3: relu(acc+bias) -> outb
// EPI 4: relu(acc+bias) -> outf AND outb   [fused E epilogue, R23]
// ---------------------------------------------------------------------------
template<int EPI, int NR>
__device__ __forceinline__
void gemm_body(char* lds,
               const u16* __restrict__ A, int lda,
               const u16* __restrict__ Bt, int ldb, int K,
               const float* __restrict__ bias,
               const float* __restrict__ st_in, int st_ld,
               float* __restrict__ outf, int outf_ld,
               u16* __restrict__ outb, int outb_ld, int nvalid,
               int mb, int nb, int stf_c0) {
  constexpr int BN = NR * 32;
  u16 (*As)[64 * 64] = reinterpret_cast<u16 (*)[64 * 64]>(lds);
  u16 (*Bs)[BN * 64] = reinterpret_cast<u16 (*)[BN * 64]>(lds + 2 * 64 * 64 * 2);
  const int t = threadIdx.x;
  const int w = t >> 6, lane = t & 63;
  const int m0 = (w & 1) << 5, n0 = (w >> 1) * (NR << 4);
  const int lr = lane & 15, lq = lane >> 4;

  f32x4 acc[2][NR] = {};
  const int nk = K >> 6;

  auto stage = [&](int kt, int buf) {
    const int kb = kt << 6;
#pragma unroll
    for (int i = 0; i < 2; ++i) {
      const int c   = (w << 7) + (i << 6) + lane;
      const int row = c >> 3;
      const int kg  = (c & 7) ^ (row & 7);
      gl_lds16(A + (size_t)(mb + row) * lda + kb + (kg << 3),
               (char*)As[buf] + c * 16);
    }
#pragma unroll
    for (int i = 0; i < NR; ++i) {
      const int c   = w * (NR * 64) + (i << 6) + lane;
      const int row = c >> 3;
      const int kg  = (c & 7) ^ (row & 7);
      gl_lds16(Bt + (size_t)(nb + row) * ldb + kb + (kg << 3),
               (char*)Bs[buf] + c * 16);
    }
  };

  stage(0, 0);
  for (int kt = 0; kt < nk; ++kt) {
    const int buf = kt & 1;
    __syncthreads();
    if (kt + 1 < nk) stage(kt + 1, buf ^ 1);
#pragma unroll
    for (int kk = 0; kk < 2; ++kk) {
      const int kg = (kk << 2) + lq;
      const int sw = (kg ^ (lr & 7)) << 3;
      bf16x8 af[2], bf[NR];
#pragma unroll
      for (int i = 0; i < 2; ++i)
        af[i] = *(const bf16x8*)&As[buf][(m0 + (i << 4) + lr) * 64 + sw];
#pragma unroll
      for (int j = 0; j < NR; ++j)
        bf[j] = *(const bf16x8*)&Bs[buf][(n0 + (j << 4) + lr) * 64 + sw];
#pragma unroll
      for (int i = 0; i < 2; ++i)
#pragma unroll
        for (int j = 0; j < NR; ++j)
          acc[i][j] = __builtin_amdgcn_mfma_f32_16x16x32_bf16(af[i], bf[j], acc[i][j], 0, 0, 0);
    }
  }

#pragma unroll
  for (int i = 0; i < 2; ++i) {
#pragma unroll
    for (int j = 0; j < NR; ++j) {
      const int cg = nb + n0 + (j << 4) + lr;
#pragma unroll
      for (int r = 0; r < 4; ++r) {
        const int rg = mb + m0 + (i << 4) + (lq << 2) + r;
        float v = acc[i][j][r];
        if (EPI == 0) {
          outf[(size_t)rg * outf_ld + cg] = v;
        } else if (EPI == 1) {
          v += st_in[(size_t)rg * st_ld + cg];
          v = v > 0.f ? v : 0.f;
          if (cg >= stf_c0) outf[(size_t)rg * outf_ld + cg] = v;
          outb[(size_t)rg * outb_ld + cg] = f2bf(v);
        } else if (EPI == 2) {
          if (cg < nvalid)
            outf[(size_t)rg * outf_ld + cg] = v + bias[cg];
        } else if (EPI == 3) {
          v += bias[cg];
          v = v > 0.f ? v : 0.f;
          outb[(size_t)rg * outb_ld + cg] = f2bf(v);
        } else {  // EPI == 4
          v += bias[cg];
          v = v > 0.f ? v : 0.f;
          outf[(size_t)rg * outf_ld + cg] = v;
          outb[(size_t)rg * outb_ld + cg] = f2bf(v);
        }
      }
    }
  }
}

template<int EPI, int NR>
__global__ __launch_bounds__(256)
void gemm128(const u16* __restrict__ A, int lda,
             const u16* __restrict__ Bt, int ldb, int K,
             const float* __restrict__ bias,
             const float* __restrict__ st_in, int st_ld,
             float* __restrict__ outf, int outf_ld,
             u16* __restrict__ outb, int outb_ld, int nvalid, int stf_c0) {
  __shared__ __align__(16) char lds[2 * 64 * 64 * 2 + 2 * NR * 32 * 64 * 2];
  gemm_body<EPI, NR>(lds, A, lda, Bt, ldb, K, bias, st_in, st_ld,
                     outf, outf_ld, outb, outb_ld, nvalid,
                     blockIdx.y << 6, blockIdx.x * (NR * 32), stf_c0);
}

// ---------------------------------------------------------------------------
// R23 fused E kernel: replaces {gemm_e split-K + e_combine}. bx<16: GEMM
// cols [0,1024) with fused bias+relu dual-store epilogue (EPI 4, K=3264
// un-split). bx>=16: zero-fill st_f/st_b cols [1024,4096). One dispatch,
// no cross-block ordering needed.
// ---------------------------------------------------------------------------
__global__ __launch_bounds__(256)
void e_fused(const u16* __restrict__ feat, const u16* __restrict__ ip_wt,
             const float* __restrict__ ip_b,
             float* __restrict__ st_f, u16* __restrict__ st_b) {
  __shared__ __align__(16) char lds[2 * 64 * 64 * 2 + 2 * 64 * 64 * 2];
  const int bx = blockIdx.x, by = blockIdx.y;
  if (bx < 16) {
    gemm_body<4, 2>(lds, feat, 3328, ip_wt, 3264, 3264, ip_b, nullptr, 0,
                    st_f, 4096, st_b, 4096, 0, by << 6, bx << 6, 0);
    return;
  }
  const int t = threadIdx.x;
  const int r  = (by << 6) + (t >> 2);
  const int c0 = (bx << 6) + ((t & 3) << 4);
  float* pf = st_f + (size_t)r * 4096 + c0;
  u16*   pb = st_b + (size_t)r * 4096 + c0;
  const float4  z4 = make_float4(0.f, 0.f, 0.f, 0.f);
  const ushort4 zu = make_ushort4(0, 0, 0, 0);
#pragma unroll
  for (int i = 0; i < 4; ++i) *(float4*)(pf + (i << 2)) = z4;
#pragma unroll
  for (int i = 0; i < 4; ++i) *(ushort4*)(pb + (i << 2)) = zu;
}

// ---------------------------------------------------------------------------
// R17 t1 kernel (8-wave 512-thread).
// ---------------------------------------------------------------------------
__global__ __launch_bounds__(512)
void gemm512e1(const u16* __restrict__ A, int lda,
               const u16* __restrict__ Bt, int ldb, int K,
               const float* __restrict__ st_in, int st_ld,
               float* __restrict__ outf, int outf_ld,
               u16* __restrict__ outb, int outb_ld, int stf_c0) {
  __shared__ __align__(16) u16 As[2][64 * 64];
  __shared__ __align__(16) u16 Bs[2][128 * 64];
  const int t = threadIdx.x;
  const int w = t >> 6, lane = t & 63;
  const int mb = blockIdx.y << 6, nb = blockIdx.x << 7;
  const int m0 = (w & 1) << 5, n0 = (w >> 1) << 5;
  const int lr = lane & 15, lq = lane >> 4;

  f32x4 acc[2][2] = {};
  const int nk = K >> 6;

  auto stage = [&](int kt, int buf) {
    const int kb = kt << 6;
    {
      const int c   = t;
      const int row = c >> 3;
      const int kg  = (c & 7) ^ (row & 7);
      gl_lds16(A + (size_t)(mb + row) * lda + kb + (kg << 3),
               (char*)As[buf] + c * 16);
    }
#pragma unroll
    for (int i = 0; i < 2; ++i) {
      const int c   = (i << 9) + t;
      const int row = c >> 3;
      const int kg  = (c & 7) ^ (row & 7);
      gl_lds16(Bt + (size_t)(nb + row) * ldb + kb + (kg << 3),
               (char*)Bs[buf] + c * 16);
    }
  };

  stage(0, 0);
  for (int kt = 0; kt < nk; ++kt) {
    const int buf = kt & 1;
    __syncthreads();
    if (kt + 1 < nk) stage(kt + 1, buf ^ 1);
#pragma unroll
    for (int kk = 0; kk < 2; ++kk) {
      const int kg = (kk << 2) + lq;
      const int sw = (kg ^ (lr & 7)) << 3;
      bf16x8 af[2], bf[2];
#pragma unroll
      for (int i = 0; i < 2; ++i)
        af[i] = *(const bf16x8*)&As[buf][(m0 + (i << 4) + lr) * 64 + sw];
#pragma unroll
      for (int j = 0; j < 2; ++j)
        bf[j] = *(const bf16x8*)&Bs[buf][(n0 + (j << 4) + lr) * 64 + sw];
#pragma unroll
      for (int i = 0; i < 2; ++i)
#pragma unroll
        for (int j = 0; j < 2; ++j)
          acc[i][j] = __builtin_amdgcn_mfma_f32_16x16x32_bf16(af[i], bf[j], acc[i][j], 0, 0, 0);
    }
  }

#pragma unroll
  for (int i = 0; i < 2; ++i)
#pragma unroll
    for (int j = 0; j < 2; ++j) {
      const int cg = nb + n0 + (j << 4) + lr;
#pragma unroll
      for (int r = 0; r < 4; ++r) {
        const int rg = mb + m0 + (i << 4) + (lq << 2) + r;
        float v = acc[i][j][r] + st_in[(size_t)rg * st_ld + cg];
        v = v > 0.f ? v : 0.f;
        if (cg >= stf_c0) outf[(size_t)rg * outf_ld + cg] = v;
        outb[(size_t)rg * outb_ld + cg] = f2bf(v);
      }
    }
}

// ---------------------------------------------------------------------------
// R15 fused weff2 + conv-GEMM (conv blocks first; weff HBM wave overlaps).
// ---------------------------------------------------------------------------
__global__ __launch_bounds__(256)
void weff_conv(const float* __restrict__ W, const u16* __restrict__ lBt,
               const u16* __restrict__ lAb, u16* __restrict__ Wt,
               const u16* __restrict__ Xb, const u16* __restrict__ Wct,
               const float* __restrict__ bias_c, u16* __restrict__ feat) {
  __shared__ __align__(16) char lds[49152];
  const int b = blockIdx.x;
  const int t = threadIdx.x;
  if (b < 416) {
    const int bx = b % 26, by = b / 26;
    gemm_body<3, 4>(lds, Xb, 512, Wct, 512, 512, bias_c, nullptr, 0,
                    nullptr, 0, feat, 3328, 3328, by << 6, bx << 7, 0);
    return;
  }
  u16*   As_ = (u16*)lds;
  u16*   Bs_ = (u16*)(lds + 8192);
  float* Wl  = (float*)(lds + 16384);
  u16*   Ct  = (u16*)(lds + 32768);
  const int b2 = b - 416;
  const int w = t >> 6, lane = t & 63;
  const int nb = (b2 & 63) << 6, kb = (b2 >> 6) << 6;
  const int m0 = (w & 1) << 5, n0 = (w >> 1) << 5;
  const int lr = lane & 15, lq = lane >> 4;

  for (int i = 0; i < 2; ++i) {
    const int c   = (w << 7) + (i << 6) + lane;
    const int row = c >> 3;
    const int kg  = (c & 7) ^ (row & 7);
    gl_lds16(lBt + (size_t)(nb + row) * 64 + (kg << 3), (char*)As_ + c * 16);
    gl_lds16(lAb + (size_t)(kb + row) * 64 + (kg << 3), (char*)Bs_ + c * 16);
  }
  for (int i = 0; i < 4; ++i) {
    const int c   = (w << 8) + (i << 6) + lane;
    const int row = c >> 4;
    const int cc  = (c & 15) ^ (row & 15);
    gl_lds16(W + (size_t)(kb + row) * 4096 + nb + (cc << 2), (char*)Wl + c * 16);
  }
  __syncthreads();

  f32x4 acc[2][2] = {};
  for (int kk = 0; kk < 2; ++kk) {
    const int kg = (kk << 2) + lq;
    const int sw = (kg ^ (lr & 7)) << 3;
    bf16x8 af[2], bf[2];
    for (int i = 0; i < 2; ++i)
      af[i] = *(const bf16x8*)&As_[(m0 + (i << 4) + lr) * 64 + sw];
    for (int j = 0; j < 2; ++j)
      bf[j] = *(const bf16x8*)&Bs_[(n0 + (j << 4) + lr) * 64 + sw];
    for (int i = 0; i < 2; ++i)
      for (int j = 0; j < 2; ++j)
        acc[i][j] = __builtin_amdgcn_mfma_f32_16x16x32_bf16(af[i], bf[j], acc[i][j], 0, 0, 0);
  }

  for (int i = 0; i < 2; ++i) {
    for (int j = 0; j < 2; ++j) {
      const int cg  = n0 + (j << 4) + lr;
      const int rg0 = m0 + (i << 4) + (lq << 2);
      const int ch  = (rg0 >> 2) ^ (cg & 15);
      const float4 wv4 = *(const float4*)&Wl[cg * 64 + (ch << 2)];
      const float wv[4] = {wv4.x, wv4.y, wv4.z, wv4.w};
      for (int r = 0; r < 4; ++r)
        Ct[(rg0 + r) * 68 + cg] =
            (wv[r] != 0.f) ? f2bf(wv[r] + 2.0f * acc[i][j][r]) : (u16)0;
    }
  }
  __syncthreads();

  const int row = t >> 2, kp = (t & 3) << 4;
  u16* dst = Wt + (size_t)(nb + row) * 4096 + kb + kp;
  const u16* src = &Ct[row * 68 + kp];
  for (int i = 0; i < 4; ++i)
    *(ushort4*)(dst + (i << 2)) = *(const ushort4*)(src + (i << 2));
}

// ---------------------------------------------------------------------------
extern "C" void kernel_launch(void* const* d_in, const int* in_sizes, int n_in,
                              void* d_out, int out_size, void* d_ws, size_t ws_size,
                              hipStream_t stream) {
  const float* x     = (const float*)d_in[0];
  const float* cw[8];
  for (int i = 0; i < 8; ++i) cw[i] = (const float*)d_in[1 + i];
  const float* convb = (const float*)d_in[9];
  const float* W     = (const float*)d_in[10];
  const float* lA    = (const float*)d_in[11];
  const float* lB    = (const float*)d_in[12];
  const float* ip_w  = (const float*)d_in[13];
  const float* ip_b  = (const float*)d_in[14];
  const float* out_w = (const float*)d_in[15];
  const float* out_b = (const float*)d_in[16];
  float* out = (float*)d_out;

  char* p = (char*)d_ws;
  u16* feat   = (u16*)p;  p += (size_t)1024 * 3328 * 2;
  u16* ip_wt  = (u16*)p;  p += (size_t)1024 * 3264 * 2;
  u16* out_wt = (u16*)p;  p += (size_t)2048 * 1024 * 2;
  u16* Wt     = (u16*)p;  p += (size_t)4096 * 4096 * 2;
  float* st_f[2];
  st_f[0] = (float*)p;    p += (size_t)1024 * 4096 * 4;
  st_f[1] = (float*)p;    p += (size_t)1024 * 4096 * 4;
  u16* st_b[2];
  st_b[0] = (u16*)p;      p += (size_t)1024 * 4096 * 2;
  st_b[1] = (u16*)p;      p += (size_t)1024 * 4096 * 2;

  // Prep buffers alias the front of st_f[1] (dead until t1 writes it).
  char* q = (char*)st_f[1];
  u16* Xb       = (u16*)q;  q += (size_t)1024 * 512 * 2;
  u16* Wct      = (u16*)q;  q += (size_t)3328 * 512 * 2;
  float* bias_c = (float*)q; q += (size_t)3328 * 4;
  u16* lBt      = (u16*)q;  q += (size_t)4096 * 64 * 2;
  u16* lAb      = (u16*)q;  q += (size_t)4096 * 64 * 2;

  // 1. fused prep
  prep_all<<<2576, 256, 0, stream>>>(x, Xb, lA, lAb, ip_w, ip_wt,
                                     out_w, out_wt, lB, lBt,
                                     cw[0], cw[1], cw[2], cw[3],
                                     cw[4], cw[5], cw[6], cw[7], convb,
                                     Wct, bias_c);

  // 2. fused W_eff + conv GEMM
  weff_conv<<<4512, 256, 0, stream>>>(W, lBt, lAb, Wt, Xb, Wct, bias_c, feat);

  // 3. t=0 fused: E GEMM (K=3264, bias+relu dual-store) + zero-fill, one
  //    dispatch (was gemm_e + e_combine).
  e_fused<<<dim3(64, 16), 256, 0, stream>>>(feat, ip_wt, ip_b,
                                            st_f[0], st_b[0]);

  // 4. t=1: K=1024 (cols >= 1024 exactly zero); 8-wave variant.
  gemm512e1<<<dim3(32, 16), 512, 0, stream>>>(st_b[0], 4096, Wt, 4096, 1024,
      st_f[0], 4096, st_f[1], 4096, st_b[1], 4096, 0);

  // 5-6. t=2,3: 64x128 tile, grid (32,16); t3's f32 store predicated to
  //      cols >= 3072.
  gemm128<1, 4><<<dim3(32, 16), 256, 0, stream>>>(st_b[1], 4096, Wt, 4096, 4096,
      nullptr, st_f[1], 4096, st_f[0], 4096, st_b[0], 4096, 4096, 0);
  gemm128<1, 4><<<dim3(32, 16), 256, 0, stream>>>(st_b[0], 4096, Wt, 4096, 4096,
      nullptr, st_f[0], 4096, st_f[1], 4096, st_b[1], 4096, 4096, 3072);

  // 7. t=4 fused: N=1024 (Wt rows 3072+), K=4096 un-split, EPI 1 with
  //    st_in = st_f[1][:,3072:], bf16-only store (stf_c0 huge suppresses
  //    the f32 write). One dispatch (was gemm_p4 + t4_combine).
  gemm128<1, 2><<<dim3(16, 16), 256, 0, stream>>>(st_b[1], 4096,
      Wt + (size_t)3072 * 4096, 4096, 4096,
      nullptr, st_f[1] + 3072, 4096, nullptr, 0,
      st_b[0] + 3072, 4096, 4096, 1 << 30);

  // 8. output: state[:, 3072:] @ out_w + out_b
  gemm128<2, 2><<<dim3(32, 16), 256, 0, stream>>>(st_b[0] + 3072, 4096, out_wt, 1024, 1024,
      out_b, nullptr, 0, out, 1968, nullptr, 0, 1968, 0);
}

// Round 13
// 345.817 us; speedup vs baseline: 1.0781x; 1.0781x over previous
//
#include <hip/hip_runtime.h>
#include <stdint.h>

typedef unsigned short u16;
typedef __attribute__((ext_vector_type(8))) short bf16x8;
typedef __attribute__((ext_vector_type(4))) float f32x4;

__device__ __forceinline__ u16 f2bf(float f) {
  union { float f; uint32_t u; } v; v.f = f;
  uint32_t u = v.u;
  return (u16)((u + 0x7fffu + ((u >> 16) & 1u)) >> 16);
}

__device__ __forceinline__ void gl_lds16(const void* g, void* l) {
  __builtin_amdgcn_global_load_lds(
      (const __attribute__((address_space(1))) uint32_t*)g,
      (__attribute__((address_space(3))) uint32_t*)l, 16, 0, 0);
}

__constant__ int c_off[9] = {0, 1024, 1808, 2384, 2784, 3040, 3184, 3248, 3264};

// ---------------------------------------------------------------------------
// Fused prep kernel (R21 compressed scatter). R24: also zero-fills
// st_f[0][:,1024:4096) (needed as t1's st_in addend; depends on nothing;
// st_f[0] is not aliased by prep scratch). Blocks [2000, 2768) handle it.
// ---------------------------------------------------------------------------
__global__ __launch_bounds__(256)
void prep_all(const float* __restrict__ x, u16* __restrict__ Xb,
              const float* __restrict__ lA, u16* __restrict__ lAb,
              const float* __restrict__ ip_w, u16* __restrict__ ip_wt,
              const float* __restrict__ out_w, u16* __restrict__ out_wt,
              const float* __restrict__ lB, u16* __restrict__ lBt,
              const float* w1, const float* w2, const float* w3, const float* w4,
              const float* w5, const float* w6, const float* w7, const float* w8,
              const float* __restrict__ cb,
              u16* __restrict__ Wct, float* __restrict__ bias_c,
              float* __restrict__ st_f0) {
  __shared__ float tile[64][65];
  int b = blockIdx.x;
  const int t = threadIdx.x;
  if (b < 512) {
    const int i = b * 256 + t;
    const float4 v = ((const float4*)x)[i];
    ((ushort4*)Xb)[i] = make_ushort4(f2bf(v.x), f2bf(v.y), f2bf(v.z), f2bf(v.w));
    return;
  }
  b -= 512;
  if (b < 256) {
    const int i = b * 256 + t;
    const float4 v = ((const float4*)lA)[i];
    ((ushort4*)lAb)[i] = make_ushort4(f2bf(v.x), f2bf(v.y), f2bf(v.z), f2bf(v.w));
    return;
  }
  b -= 256;
  if (b < 1392) {
    const float* src; u16* dst; int R, C, bx, by;
    if (b < 816)        { src = ip_w;  dst = ip_wt;  R = 3264; C = 1024; bx = b % 16; by = b / 16; }
    else if (b < 1328)  { b -= 816;  src = out_w; dst = out_wt; R = 1024; C = 1968; bx = b % 32; by = b / 32; }
    else                { b -= 1328; src = lB;    dst = lBt;    R = 64;   C = 4096; bx = b;      by = 0; }
    const int rb = by << 6, cbs = bx << 6;
    for (int i = 0; i < 16; ++i) {
      const int idx = t + (i << 8);
      const int r = idx >> 6, c = idx & 63;
      float v = 0.f;
      if (cbs + c < C) v = src[(size_t)(rb + r) * C + cbs + c];
      tile[r][c] = v;
    }
    __syncthreads();
    const int c = t & 63, q = t >> 6;
    u16* dcol = dst + (size_t)(cbs + c) * R + rb;
    for (int v4 = 0; v4 < 4; ++v4) {
      const int r0 = (q << 4) + (v4 << 2);
      *(ushort4*)(dcol + r0) = make_ushort4(
          f2bf(tile[r0][c]), f2bf(tile[r0 + 1][c]),
          f2bf(tile[r0 + 2][c]), f2bf(tile[r0 + 3][c]));
    }
    return;
  }
  b -= 1392;
  if (b < 416) {
    // Wct scatter: 8 rows per block. o0 in [0, 3328).
    const int o0 = b << 3;
    for (int i = t; i < 1024; i += 256)
      *(ushort4*)(Wct + (size_t)(o0 + (i >> 7)) * 512 + ((i & 127) << 2)) =
          make_ushort4(0, 0, 0, 0);
    __syncthreads();
    const float* ws[8] = {w1, w2, w3, w4, w5, w6, w7, w8};
    for (int rr = 0; rr < 8; ++rr) {
      const int o = o0 + rr;
      if (o >= 3264) {
        if (t == 0) bias_c[o] = 0.f;
        continue;
      }
      u16* row = Wct + (size_t)o * 512;
      int kidx = 0;
      while (o >= c_off[kidx + 1]) ++kidx;
      const int ks = kidx + 1;
      const int s  = 8 - kidx;
      const int r  = o - c_off[kidx];
      const int f   = r / (s * s);
      const int rem = r - f * s * s;
      const int oi  = rem / s;
      const int oj  = rem - oi * s;
      const float* w = ws[kidx] + (size_t)f * 8 * ks * ks;
      const int ne = 8 * ks * ks;
      for (int e = t; e < ne; e += 256) {
        const int c  = e / (ks * ks);
        const int er = e - c * ks * ks;
        const int di = er / ks;
        const int dj = er - di * ks;
        row[((oi + di) * 8 + (oj + dj)) * 8 + c] = f2bf(w[(c * ks + di) * ks + dj]);
      }
      if (t == 0) bias_c[o] = cb[kidx * 16 + f];
    }
    return;
  }
  // st_f0 zero-fill: cols [1024,4096) of 1024 rows = 3M floats over 768
  // blocks: block handles 4 rows x 3072 cols / (256 threads x float4).
  const int zb = b - 416;               // [0, 768)
  const int row0 = zb / 0x300 * 4;      // 768 blocks -> wait; compute below
  // 1024 rows x 3072 cols = 3,145,728 floats = 786,432 float4 / 768 blocks
  // = 1024 float4/block = 4 per thread.
  const int base = zb * 1024 + t;       // float4 index within the region
  for (int i = 0; i < 4; ++i) {
    const int idx = base + (i << 8);    // [0, 786432)
    const int r = idx / 768, c = idx - r * 768;   // 768 float4 per row
    *(float4*)&st_f0[(size_t)r * 4096 + 1024 + (c << 2)] =
        make_float4(0.f, 0.f, 0.f, 0.f);
  }
}

// ---------------------------------------------------------------------------
// R15 GEMM body (the proven inner loop): 64x(NR*32) tile, 4 waves, BK=64,
// dbuf LDS via __syncthreads, XOR-swizzled, gl_lds staging.
// EPI 0: outf = acc (f32 partial)   EPI 1: relu(acc+st_in) -> outf?,outb
// EPI 2: acc+bias -> outf, cg<nvalid  EPI 3: relu(acc+bias) -> outb
// ---------------------------------------------------------------------------
template<int EPI, int NR>
__device__ __forceinline__
void gemm_body(char* lds,
               const u16* __restrict__ A, int lda,
               const u16* __restrict__ Bt, int ldb, int K,
               const float* __restrict__ bias,
               const float* __restrict__ st_in, int st_ld,
               float* __restrict__ outf, int outf_ld,
               u16* __restrict__ outb, int outb_ld, int nvalid,
               int mb, int nb, int stf_c0) {
  constexpr int BN = NR * 32;
  u16 (*As)[64 * 64] = reinterpret_cast<u16 (*)[64 * 64]>(lds);
  u16 (*Bs)[BN * 64] = reinterpret_cast<u16 (*)[BN * 64]>(lds + 2 * 64 * 64 * 2);
  const int t = threadIdx.x;
  const int w = t >> 6, lane = t & 63;
  const int m0 = (w & 1) << 5, n0 = (w >> 1) * (NR << 4);
  const int lr = lane & 15, lq = lane >> 4;

  f32x4 acc[2][NR] = {};
  const int nk = K >> 6;

  auto stage = [&](int kt, int buf) {
    const int kb = kt << 6;
#pragma unroll
    for (int i = 0; i < 2; ++i) {
      const int c   = (w << 7) + (i << 6) + lane;
      const int row = c >> 3;
      const int kg  = (c & 7) ^ (row & 7);
      gl_lds16(A + (size_t)(mb + row) * lda + kb + (kg << 3),
               (char*)As[buf] + c * 16);
    }
#pragma unroll
    for (int i = 0; i < NR; ++i) {
      const int c   = w * (NR * 64) + (i << 6) + lane;
      const int row = c >> 3;
      const int kg  = (c & 7) ^ (row & 7);
      gl_lds16(Bt + (size_t)(nb + row) * ldb + kb + (kg << 3),
               (char*)Bs[buf] + c * 16);
    }
  };

  stage(0, 0);
  for (int kt = 0; kt < nk; ++kt) {
    const int buf = kt & 1;
    __syncthreads();
    if (kt + 1 < nk) stage(kt + 1, buf ^ 1);
#pragma unroll
    for (int kk = 0; kk < 2; ++kk) {
      const int kg = (kk << 2) + lq;
      const int sw = (kg ^ (lr & 7)) << 3;
      bf16x8 af[2], bf[NR];
#pragma unroll
      for (int i = 0; i < 2; ++i)
        af[i] = *(const bf16x8*)&As[buf][(m0 + (i << 4) + lr) * 64 + sw];
#pragma unroll
      for (int j = 0; j < NR; ++j)
        bf[j] = *(const bf16x8*)&Bs[buf][(n0 + (j << 4) + lr) * 64 + sw];
#pragma unroll
      for (int i = 0; i < 2; ++i)
#pragma unroll
        for (int j = 0; j < NR; ++j)
          acc[i][j] = __builtin_amdgcn_mfma_f32_16x16x32_bf16(af[i], bf[j], acc[i][j], 0, 0, 0);
    }
  }

#pragma unroll
  for (int i = 0; i < 2; ++i) {
#pragma unroll
    for (int j = 0; j < NR; ++j) {
      const int cg = nb + n0 + (j << 4) + lr;
#pragma unroll
      for (int r = 0; r < 4; ++r) {
        const int rg = mb + m0 + (i << 4) + (lq << 2) + r;
        float v = acc[i][j][r];
        if (EPI == 0) {
          outf[(size_t)rg * outf_ld + cg] = v;
        } else if (EPI == 1) {
          v += st_in[(size_t)rg * st_ld + cg];
          v = v > 0.f ? v : 0.f;
          if (cg >= stf_c0) outf[(size_t)rg * outf_ld + cg] = v;
          outb[(size_t)rg * outb_ld + cg] = f2bf(v);
        } else if (EPI == 2) {
          if (cg < nvalid)
            outf[(size_t)rg * outf_ld + cg] = v + bias[cg];
        } else {
          v += bias[cg];
          v = v > 0.f ? v : 0.f;
          outb[(size_t)rg * outb_ld + cg] = f2bf(v);
        }
      }
    }
  }
}

template<int EPI, int NR>
__global__ __launch_bounds__(256)
void gemm128(const u16* __restrict__ A, int lda,
             const u16* __restrict__ Bt, int ldb, int K,
             const float* __restrict__ bias,
             const float* __restrict__ st_in, int st_ld,
             float* __restrict__ outf, int outf_ld,
             u16* __restrict__ outb, int outb_ld, int nvalid, int stf_c0) {
  __shared__ __align__(16) char lds[2 * 64 * 64 * 2 + 2 * NR * 32 * 64 * 2];
  gemm_body<EPI, NR>(lds, A, lda, Bt, ldb, K, bias, st_in, st_ld,
                     outf, outf_ld, outb, outb_ld, nvalid,
                     blockIdx.y << 6, blockIdx.x * (NR * 32), stf_c0);
}

// ---------------------------------------------------------------------------
// t1 kernel (8-wave 512-thread; in the noise band vs 4-wave, kept).
// ---------------------------------------------------------------------------
__global__ __launch_bounds__(512)
void gemm512e1(const u16* __restrict__ A, int lda,
               const u16* __restrict__ Bt, int ldb, int K,
               const float* __restrict__ st_in, int st_ld,
               float* __restrict__ outf, int outf_ld,
               u16* __restrict__ outb, int outb_ld, int stf_c0) {
  __shared__ __align__(16) u16 As[2][64 * 64];
  __shared__ __align__(16) u16 Bs[2][128 * 64];
  const int t = threadIdx.x;
  const int w = t >> 6, lane = t & 63;
  const int mb = blockIdx.y << 6, nb = blockIdx.x << 7;
  const int m0 = (w & 1) << 5, n0 = (w >> 1) << 5;
  const int lr = lane & 15, lq = lane >> 4;

  f32x4 acc[2][2] = {};
  const int nk = K >> 6;

  auto stage = [&](int kt, int buf) {
    const int kb = kt << 6;
    {
      const int c   = t;
      const int row = c >> 3;
      const int kg  = (c & 7) ^ (row & 7);
      gl_lds16(A + (size_t)(mb + row) * lda + kb + (kg << 3),
               (char*)As[buf] + c * 16);
    }
#pragma unroll
    for (int i = 0; i < 2; ++i) {
      const int c   = (i << 9) + t;
      const int row = c >> 3;
      const int kg  = (c & 7) ^ (row & 7);
      gl_lds16(Bt + (size_t)(nb + row) * ldb + kb + (kg << 3),
               (char*)Bs[buf] + c * 16);
    }
  };

  stage(0, 0);
  for (int kt = 0; kt < nk; ++kt) {
    const int buf = kt & 1;
    __syncthreads();
    if (kt + 1 < nk) stage(kt + 1, buf ^ 1);
#pragma unroll
    for (int kk = 0; kk < 2; ++kk) {
      const int kg = (kk << 2) + lq;
      const int sw = (kg ^ (lr & 7)) << 3;
      bf16x8 af[2], bf[2];
#pragma unroll
      for (int i = 0; i < 2; ++i)
        af[i] = *(const bf16x8*)&As[buf][(m0 + (i << 4) + lr) * 64 + sw];
#pragma unroll
      for (int j = 0; j < 2; ++j)
        bf[j] = *(const bf16x8*)&Bs[buf][(n0 + (j << 4) + lr) * 64 + sw];
#pragma unroll
      for (int i = 0; i < 2; ++i)
#pragma unroll
        for (int j = 0; j < 2; ++j)
          acc[i][j] = __builtin_amdgcn_mfma_f32_16x16x32_bf16(af[i], bf[j], acc[i][j], 0, 0, 0);
    }
  }

#pragma unroll
  for (int i = 0; i < 2; ++i)
#pragma unroll
    for (int j = 0; j < 2; ++j) {
      const int cg = nb + n0 + (j << 4) + lr;
#pragma unroll
      for (int r = 0; r < 4; ++r) {
        const int rg = mb + m0 + (i << 4) + (lq << 2) + r;
        float v = acc[i][j][r] + st_in[(size_t)rg * st_ld + cg];
        v = v > 0.f ? v : 0.f;
        if (cg >= stf_c0) outf[(size_t)rg * outf_ld + cg] = v;
        outb[(size_t)rg * outb_ld + cg] = f2bf(v);
      }
    }
}

// ---------------------------------------------------------------------------
// R15 fused weff2 + conv-GEMM (conv blocks first; weff HBM wave overlaps).
// ---------------------------------------------------------------------------
__global__ __launch_bounds__(256)
void weff_conv(const float* __restrict__ W, const u16* __restrict__ lBt,
               const u16* __restrict__ lAb, u16* __restrict__ Wt,
               const u16* __restrict__ Xb, const u16* __restrict__ Wct,
               const float* __restrict__ bias_c, u16* __restrict__ feat) {
  __shared__ __align__(16) char lds[49152];
  const int b = blockIdx.x;
  const int t = threadIdx.x;
  if (b < 416) {
    const int bx = b % 26, by = b / 26;
    gemm_body<3, 4>(lds, Xb, 512, Wct, 512, 512, bias_c, nullptr, 0,
                    nullptr, 0, feat, 3328, 3328, by << 6, bx << 7, 0);
    return;
  }
  u16*   As_ = (u16*)lds;
  u16*   Bs_ = (u16*)(lds + 8192);
  float* Wl  = (float*)(lds + 16384);
  u16*   Ct  = (u16*)(lds + 32768);
  const int b2 = b - 416;
  const int w = t >> 6, lane = t & 63;
  const int nb = (b2 & 63) << 6, kb = (b2 >> 6) << 6;
  const int m0 = (w & 1) << 5, n0 = (w >> 1) << 5;
  const int lr = lane & 15, lq = lane >> 4;

  for (int i = 0; i < 2; ++i) {
    const int c   = (w << 7) + (i << 6) + lane;
    const int row = c >> 3;
    const int kg  = (c & 7) ^ (row & 7);
    gl_lds16(lBt + (size_t)(nb + row) * 64 + (kg << 3), (char*)As_ + c * 16);
    gl_lds16(lAb + (size_t)(kb + row) * 64 + (kg << 3), (char*)Bs_ + c * 16);
  }
  for (int i = 0; i < 4; ++i) {
    const int c   = (w << 8) + (i << 6) + lane;
    const int row = c >> 4;
    const int cc  = (c & 15) ^ (row & 15);
    gl_lds16(W + (size_t)(kb + row) * 4096 + nb + (cc << 2), (char*)Wl + c * 16);
  }
  __syncthreads();

  f32x4 acc[2][2] = {};
  for (int kk = 0; kk < 2; ++kk) {
    const int kg = (kk << 2) + lq;
    const int sw = (kg ^ (lr & 7)) << 3;
    bf16x8 af[2], bf[2];
    for (int i = 0; i < 2; ++i)
      af[i] = *(const bf16x8*)&As_[(m0 + (i << 4) + lr) * 64 + sw];
    for (int j = 0; j < 2; ++j)
      bf[j] = *(const bf16x8*)&Bs_[(n0 + (j << 4) + lr) * 64 + sw];
    for (int i = 0; i < 2; ++i)
      for (int j = 0; j < 2; ++j)
        acc[i][j] = __builtin_amdgcn_mfma_f32_16x16x32_bf16(af[i], bf[j], acc[i][j], 0, 0, 0);
  }

  for (int i = 0; i < 2; ++i) {
    for (int j = 0; j < 2; ++j) {
      const int cg  = n0 + (j << 4) + lr;
      const int rg0 = m0 + (i << 4) + (lq << 2);
      const int ch  = (rg0 >> 2) ^ (cg & 15);
      const float4 wv4 = *(const float4*)&Wl[cg * 64 + (ch << 2)];
      const float wv[4] = {wv4.x, wv4.y, wv4.z, wv4.w};
      for (int r = 0; r < 4; ++r)
        Ct[(rg0 + r) * 68 + cg] =
            (wv[r] != 0.f) ? f2bf(wv[r] + 2.0f * acc[i][j][r]) : (u16)0;
    }
  }
  __syncthreads();

  const int row = t >> 2, kp = (t & 3) << 4;
  u16* dst = Wt + (size_t)(nb + row) * 4096 + kb + kp;
  const u16* src = &Ct[row * 68 + kp];
  for (int i = 0; i < 4; ++i)
    *(ushort4*)(dst + (i << 2)) = *(const ushort4*)(src + (i << 2));
}

// ---------------------------------------------------------------------------
// E-stage GEMM, split-K=4 (z: 13,13,13,12 K-iters from k0 = z*832).
// ---------------------------------------------------------------------------
__global__ __launch_bounds__(256)
void gemm_e(const u16* __restrict__ A, const u16* __restrict__ Bt,
            float* __restrict__ part) {
  __shared__ __align__(16) char lds[49152];
  const int z = blockIdx.z;
  const int k0 = z * 832;
  const int nk = (z == 3) ? 12 : 13;
  gemm_body<0, 4>(lds, A + k0, 3328, Bt + k0, 3264, nk << 6,
                  nullptr, nullptr, 0, part + ((size_t)z << 20), 1024,
                  nullptr, 0, 0, blockIdx.y << 6, blockIdx.x << 7, 0);
}

// ---------------------------------------------------------------------------
// t=4 partial GEMM, split-K=4 (grid 1024 = 4 blocks/CU regime).
// ---------------------------------------------------------------------------
__global__ __launch_bounds__(256)
void gemm_p4(const u16* __restrict__ A, const u16* __restrict__ Bt,
             float* __restrict__ part) {
  __shared__ __align__(16) char lds[32768];
  const int z = blockIdx.z;
  gemm_body<0, 2>(lds, A + (z << 10), 4096, Bt + (z << 10), 4096, 1024,
                  nullptr, nullptr, 0, part + ((size_t)z << 20), 1024,
                  nullptr, 0, 0, blockIdx.y << 6, blockIdx.x << 6, 0);
}

// ---------------------------------------------------------------------------
// E combine (R24: cols < 1024 only — st_f zeros moved to prep; st_b zeros
// for cols >= 1024 were never read (t1 reads K=1024; t2 overwrites st_b)).
// Grid 1024 blocks over 1024x1024 region.
// ---------------------------------------------------------------------------
__global__ __launch_bounds__(256)
void e_combine(const float* __restrict__ part, const float* __restrict__ bias,
               float* __restrict__ st_f, u16* __restrict__ st_b) {
  const int i = (blockIdx.x * 256 + threadIdx.x) << 2;   // over 1024x1024
  const int row = i >> 10, col = i & 1023;
  const int pi = i;
  const float4 a = *(const float4*)&part[pi];
  const float4 b = *(const float4*)&part[1024 * 1024 + pi];
  const float4 c = *(const float4*)&part[2 * 1024 * 1024 + pi];
  const float4 d = *(const float4*)&part[3 * 1024 * 1024 + pi];
  const float4 bs = *(const float4*)&bias[col];
  float v[4] = {a.x + b.x + c.x + d.x + bs.x, a.y + b.y + c.y + d.y + bs.y,
                a.z + b.z + c.z + d.z + bs.z, a.w + b.w + c.w + d.w + bs.w};
  u16 o[4];
  for (int r = 0; r < 4; ++r) {
    v[r] = v[r] > 0.f ? v[r] : 0.f;
    o[r] = f2bf(v[r]);
  }
  *(float4*)&st_f[(size_t)row * 4096 + col] = make_float4(v[0], v[1], v[2], v[3]);
  *(ushort4*)&st_b[(size_t)row * 4096 + col] = make_ushort4(o[0], o[1], o[2], o[3]);
}

// ---------------------------------------------------------------------------
// t=4 combine (no f32 state store; t4's st_f output is dead).
// ---------------------------------------------------------------------------
__global__ __launch_bounds__(256)
void t4_combine(const float* __restrict__ part, const float* __restrict__ st_in,
                u16* __restrict__ st_b) {
  const int i = (blockIdx.x * 256 + threadIdx.x) << 2;
  const int r = i >> 10, c = i & 1023;
  const float4 a  = *(const float4*)&part[i];
  const float4 b  = *(const float4*)&part[(1 << 20) + i];
  const float4 cc = *(const float4*)&part[(2 << 20) + i];
  const float4 d  = *(const float4*)&part[(3 << 20) + i];
  const float4 s  = *(const float4*)&st_in[(size_t)r * 4096 + 3072 + c];
  float v[4] = {a.x + b.x + cc.x + d.x + s.x, a.y + b.y + cc.y + d.y + s.y,
                a.z + b.z + cc.z + d.z + s.z, a.w + b.w + cc.w + d.w + s.w};
  u16 o[4];
  for (int k = 0; k < 4; ++k) {
    v[k] = v[k] > 0.f ? v[k] : 0.f;
    o[k] = f2bf(v[k]);
  }
  *(ushort4*)&st_b[(size_t)r * 4096 + 3072 + c] = make_ushort4(o[0], o[1], o[2], o[3]);
}

// ---------------------------------------------------------------------------
extern "C" void kernel_launch(void* const* d_in, const int* in_sizes, int n_in,
                              void* d_out, int out_size, void* d_ws, size_t ws_size,
                              hipStream_t stream) {
  const float* x     = (const float*)d_in[0];
  const float* cw[8];
  for (int i = 0; i < 8; ++i) cw[i] = (const float*)d_in[1 + i];
  const float* convb = (const float*)d_in[9];
  const float* W     = (const float*)d_in[10];
  const float* lA    = (const float*)d_in[11];
  const float* lB    = (const float*)d_in[12];
  const float* ip_w  = (const float*)d_in[13];
  const float* ip_b  = (const float*)d_in[14];
  const float* out_w = (const float*)d_in[15];
  const float* out_b = (const float*)d_in[16];
  float* out = (float*)d_out;

  char* p = (char*)d_ws;
  u16* feat   = (u16*)p;  p += (size_t)1024 * 3328 * 2;
  u16* ip_wt  = (u16*)p;  p += (size_t)1024 * 3264 * 2;
  u16* out_wt = (u16*)p;  p += (size_t)2048 * 1024 * 2;
  u16* Wt     = (u16*)p;  p += (size_t)4096 * 4096 * 2;
  float* st_f[2];
  st_f[0] = (float*)p;    p += (size_t)1024 * 4096 * 4;
  st_f[1] = (float*)p;    p += (size_t)1024 * 4096 * 4;
  u16* st_b[2];
  st_b[0] = (u16*)p;      p += (size_t)1024 * 4096 * 2;
  st_b[1] = (u16*)p;      p += (size_t)1024 * 4096 * 2;

  // Prep buffers alias the front of st_f[1]; Epart reuses all of st_f[1];
  // t=4 partials reuse st_f[0] (dead after t3 reads it).
  char* q = (char*)st_f[1];
  u16* Xb       = (u16*)q;  q += (size_t)1024 * 512 * 2;
  u16* Wct      = (u16*)q;  q += (size_t)3328 * 512 * 2;
  float* bias_c = (float*)q; q += (size_t)3328 * 4;
  u16* lBt      = (u16*)q;  q += (size_t)4096 * 64 * 2;
  u16* lAb      = (u16*)q;  q += (size_t)4096 * 64 * 2;
  float* Epart  = (float*)st_f[1];
  float* Tpart  = (float*)st_f[0];

  // 1. fused prep (grid 3344: 512 x + 256 lA + 1392 transpose + 416 scatter
  //    + 768 st_f0 zero-fill)
  prep_all<<<3344, 256, 0, stream>>>(x, Xb, lA, lAb, ip_w, ip_wt,
                                     out_w, out_wt, lB, lBt,
                                     cw[0], cw[1], cw[2], cw[3],
                                     cw[4], cw[5], cw[6], cw[7], convb,
                                     Wct, bias_c, st_f[0]);

  // 2. fused W_eff + conv GEMM
  weff_conv<<<4512, 256, 0, stream>>>(W, lBt, lAb, Wt, Xb, Wct, bias_c, feat);

  // 3-4. t=0: split-K=4 E + combine (cols < 1024 only now)
  gemm_e<<<dim3(8, 16, 4), 256, 0, stream>>>(feat, ip_wt, Epart);
  e_combine<<<1024, 256, 0, stream>>>(Epart, ip_b, st_f[0], st_b[0]);

  // 5. t=1: K=1024 (cols >= 1024 exactly zero); 8-wave variant.
  gemm512e1<<<dim3(32, 16), 512, 0, stream>>>(st_b[0], 4096, Wt, 4096, 1024,
      st_f[0], 4096, st_f[1], 4096, st_b[1], 4096, 0);

  // 6-7. t=2,3: 64x128 tile, grid (32,16); t3's f32 store predicated to
  //      cols >= 3072.
  gemm128<1, 4><<<dim3(32, 16), 256, 0, stream>>>(st_b[1], 4096, Wt, 4096, 4096,
      nullptr, st_f[1], 4096, st_f[0], 4096, st_b[0], 4096, 4096, 0);
  gemm128<1, 4><<<dim3(32, 16), 256, 0, stream>>>(st_b[0], 4096, Wt, 4096, 4096,
      nullptr, st_f[0], 4096, st_f[1], 4096, st_b[1], 4096, 4096, 3072);

  // 8-9. t=4: N=1024 (Wt rows 3072+), split-K=4
  gemm_p4<<<dim3(16, 16, 4), 256, 0, stream>>>(st_b[1],
      Wt + (size_t)3072 * 4096, Tpart);
  t4_combine<<<1024, 256, 0, stream>>>(Tpart, st_f[1], st_b[0]);

  // 10. output: state[:, 3072:] @ out_w + out_b
  gemm128<2, 2><<<dim3(32, 16), 256, 0, stream>>>(st_b[0] + 3072, 4096, out_wt, 1024, 1024,
      out_b, nullptr, 0, out, 1968, nullptr, 0, 1968, 0);
}